// Round 7
// baseline (161.475 us; speedup 1.0000x reference)
//
#include <hip/hip_runtime.h>
#include <hip/hip_bf16.h>

// MoLoRA = base linear + top-2 routed LoRA.
//   Abuf[T,2176] = [ bf16(x) | bf16(alpha*cw*(x@A2^T)) ]      (A2 = A_w as [128,2048])
//   Bfull[O,2176] = [ bf16(W) | bf16(B2^T) ]   (B2[e*16+r,o]=B_w[e,o,r])
//   out[T,O] = Abuf @ Bfull^T     -- single bf16 MFMA GEMM, K=2176
// T=4096, H=2048, O=2048, E=8, R=16, Kaug=2176.
//
// R1: XOR k-chunk LDS swizzle -> bank conflicts 1.34e7 -> 0.
// R3/R4: GEMM mega-block / ks-split: flat -> 2-barrier structures plateau ~30%
//        (m97 ceiling); m201-class schedules need 256^2 tiles = 256 blocks,
//        our M*N only yields 128 -> structurally excluded. GEMM floor ~40us.
// R5: GEMM 128x128, 2 blocks/CU + counted vmcnt: 40.6us, Mfma 35.4%. KEEP.
// R6: 4-wave 68KB-LDS merge cratered: router BLOCK LATENCY ~50us at 4 waves.
// R7: 0-LDS split regressed: 1 wave/SIMD latency chains.
// R8: router at 512 thr (8 waves): block latency ~13us. Best total 158.97.
// R9: overlap prep under router. Router grid = 256 = 1 block/CU (70KB LDS);
//     a second 70KB block fits per CU -> append prep blocks (512-thr, LDS
//     unused) to the SAME dispatch: prep streams co-resident with router
//     compute instead of serially after it. A2 race broken by a ~1.5us
//     a2_prep micro-dispatch. Router/GEMM code R8-verbatim.

typedef __bf16 bf16x8 __attribute__((ext_vector_type(8)));
typedef float f32x4 __attribute__((ext_vector_type(4)));

__device__ __forceinline__ __bf16 f2bf(float f) { return (__bf16)f; }  // RNE (v_cvt_pk_bf16_f32)

__device__ __forceinline__ void ld_lds16(const void* g, void* l) {
  __builtin_amdgcn_global_load_lds((__attribute__((address_space(1))) void*)g,
                                   (__attribute__((address_space(3))) void*)l,
                                   16, 0, 0);
}

// ---------------- K0: A_w -> A2 bf16 (tiny: 1 MB read, 0.5 MB write) ----------------
__global__ __launch_bounds__(256) void a2_prep(const float* __restrict__ Aw,
                                               __bf16* __restrict__ A2) {
  const int row = blockIdx.x;         // 0..127
  const int c = threadIdx.x * 8;      // 0..2040
  const float* src = Aw + (size_t)row * 2048 + c;
  float4 a = *(const float4*)src;
  float4 d = *(const float4*)(src + 4);
  bf16x8 v;
  v[0] = f2bf(a.x); v[1] = f2bf(a.y); v[2] = f2bf(a.z); v[3] = f2bf(a.w);
  v[4] = f2bf(d.x); v[5] = f2bf(d.y); v[6] = f2bf(d.z); v[7] = f2bf(d.w);
  *(bf16x8*)(A2 + (size_t)row * 2048 + c) = v;
}

// ---------------- K1: fused router + LoRA-down + co-resident prep ----------------
// grid 1312 x 512:
//   b in [0,256):     router (R8-verbatim): 16 tokens, 8 waves, 70KB LDS
//   b in [256,1280):  W 2-row convert -> Bfull[:,0:2048]   (LDS unused)
//   b in [1280,1312): B_w pack -> Bfull[:,2048:2176]       (LDS unused)
// Router blocks fill 256 CUs at 1/CU; prep blocks co-schedule into the second
// 70KB LDS slot per CU and stream under the router's compute phases.
__global__ __launch_bounds__(512) void fused_pre(
    const float* __restrict__ x, const float* __restrict__ gw,
    const __bf16* __restrict__ A2, const float* __restrict__ W,
    const float* __restrict__ Bw, __bf16* __restrict__ Abuf,
    __bf16* __restrict__ Bfull) {
  __shared__ __align__(16) __bf16 xs[16][2056];  // 64.25 KB, +8 pad
  __shared__ float red[8][16][8];
  __shared__ float cws[16][8];
  const int b = blockIdx.x;
  const int tid = threadIdx.x;

  if (b >= 256) {
    const int pb = b - 256;
    if (pb < 1024) {
      // ---- W 2 rows -> bf16 -> Bfull[row, 0:2048] ----
      const int row = pb * 2 + (tid >> 8);
      const int c = (tid & 255) * 8;
      const float* src = W + (size_t)row * 2048 + c;
      float4 a = *(const float4*)src;
      float4 d = *(const float4*)(src + 4);
      bf16x8 v;
      v[0] = f2bf(a.x); v[1] = f2bf(a.y); v[2] = f2bf(a.z); v[3] = f2bf(a.w);
      v[4] = f2bf(d.x); v[5] = f2bf(d.y); v[6] = f2bf(d.z); v[7] = f2bf(d.w);
      *(bf16x8*)(Bfull + (size_t)row * 2176 + c) = v;
    } else {
      // ---- pack B_w [E,O,R] -> Bfull[o, 2048 + e*16 + r] ----
      const int idx = (pb - 1024) * 512 + tid;  // 0..16383
      const int e = idx >> 11, o = idx & 2047;
      const float4* s = (const float4*)(Bw + ((size_t)e * 2048 + o) * 16);
      float4 v0 = s[0], v1 = s[1], v2 = s[2], v3 = s[3];
      __bf16* d = Bfull + (size_t)o * 2176 + 2048 + e * 16;
      bf16x8 lo, hi;
      lo[0] = f2bf(v0.x); lo[1] = f2bf(v0.y); lo[2] = f2bf(v0.z); lo[3] = f2bf(v0.w);
      lo[4] = f2bf(v1.x); lo[5] = f2bf(v1.y); lo[6] = f2bf(v1.z); lo[7] = f2bf(v1.w);
      hi[0] = f2bf(v2.x); hi[1] = f2bf(v2.y); hi[2] = f2bf(v2.z); hi[3] = f2bf(v2.w);
      hi[4] = f2bf(v3.x); hi[5] = f2bf(v3.y); hi[6] = f2bf(v3.z); hi[7] = f2bf(v3.w);
      *(bf16x8*)d = lo;
      *(bf16x8*)(d + 8) = hi;
    }
    return;
  }

  // ================= router block (R8-verbatim): 16 tokens, 8 waves =================
  const int wave = tid >> 6, lane = tid & 63;
  const int t0 = b * 16;

  // ---- phase 1: two token-rows per iteration, fully coalesced ----
  {
    const int half = tid >> 8;        // 0/1: which row of the pair
    const int tid2 = tid & 255;
#pragma unroll 4
    for (int i2 = 0; i2 < 8; ++i2) {
      const int i = i2 * 2 + half;
      const float* xr = x + (size_t)(t0 + i) * 2048 + tid2 * 8;
      float4 a = *(const float4*)xr;
      float4 bb = *(const float4*)(xr + 4);
      bf16x8 v;
      v[0] = f2bf(a.x); v[1] = f2bf(a.y); v[2] = f2bf(a.z); v[3] = f2bf(a.w);
      v[4] = f2bf(bb.x); v[5] = f2bf(bb.y); v[6] = f2bf(bb.z); v[7] = f2bf(bb.w);
      *(bf16x8*)(Abuf + (size_t)(t0 + i) * 2176 + tid2 * 8) = v;
      *(bf16x8*)&xs[i][tid2 * 8] = v;
    }
  }
  __syncthreads();

  // ---- phase 2: logits from bf16 x; 32 slices of 64 elems per token ----
  const int tok = tid & 15, slc = tid >> 4;  // slc in [0,32)
  const int c0 = slc * 64;
  float acc[8] = {0, 0, 0, 0, 0, 0, 0, 0};
  for (int j8 = 0; j8 < 8; ++j8) {
    bf16x8 xv = *(const bf16x8*)&xs[tok][c0 + j8 * 8];
    float xf[8];
#pragma unroll
    for (int j = 0; j < 8; ++j) xf[j] = (float)xv[j];
#pragma unroll
    for (int e = 0; e < 8; ++e) {
      float4 g0 = *(const float4*)(gw + e * 2048 + c0 + j8 * 8);
      float4 g1 = *(const float4*)(gw + e * 2048 + c0 + j8 * 8 + 4);
      acc[e] += xf[0] * g0.x + xf[1] * g0.y + xf[2] * g0.z + xf[3] * g0.w +
                xf[4] * g1.x + xf[5] * g1.y + xf[6] * g1.z + xf[7] * g1.w;
    }
  }
#pragma unroll
  for (int e = 0; e < 8; ++e) {
    acc[e] += __shfl_down(acc[e], 16);
    acc[e] += __shfl_down(acc[e], 32);
  }
  if (lane < 16) {
#pragma unroll
    for (int e = 0; e < 8; ++e) red[wave][lane][e] = acc[e];
  }
  __syncthreads();
  if (tid < 16) {
    float lg[8];
#pragma unroll
    for (int e = 0; e < 8; ++e)
      lg[e] = red[0][tid][e] + red[1][tid][e] + red[2][tid][e] + red[3][tid][e] +
              red[4][tid][e] + red[5][tid][e] + red[6][tid][e] + red[7][tid][e];
    int a = 0;
    for (int e = 1; e < 8; ++e) if (lg[e] > lg[a]) a = e;
    int bb = (a == 0) ? 1 : 0;
    for (int e = 0; e < 8; ++e) if (e != a && lg[e] > lg[bb]) bb = e;
    const float d = __expf(lg[bb] - lg[a]);
    float o[8] = {0, 0, 0, 0, 0, 0, 0, 0};
    o[a] = 1.0f / (1.0f + d);
    o[bb] = d / (1.0f + d);
#pragma unroll
    for (int e = 0; e < 8; ++e) cws[tid][e] = o[e];
  }
  __syncthreads();

  // ---- phase 3: t = xs @ A2^T, one expert per wave ----
  const int m = lane & 15, q = lane >> 4;
  const int nt = wave;  // expert index
  f32x4 tacc = {};
  for (int ks = 0; ks < 64; ++ks) {
    bf16x8 af = *(const bf16x8*)&xs[m][ks * 32 + q * 8];
    bf16x8 bfg = *(const bf16x8*)(A2 + (size_t)(nt * 16 + m) * 2048 +
                                  ks * 32 + q * 8);
    tacc = __builtin_amdgcn_mfma_f32_16x16x32_bf16(af, bfg, tacc, 0, 0, 0);
  }
  // ---- phase 4: scale + store. C layout: col=lane&15, row=q*4+reg ----
#pragma unroll
  for (int rg = 0; rg < 4; ++rg) {
    const int trow = q * 4 + rg;
    const float s = tacc[rg] * 16.0f * cws[trow][nt];
    Abuf[(size_t)(t0 + trow) * 2176 + 2048 + nt * 16 + m] = f2bf(s);
  }
}

// ---------------- K2: multi-block MFMA GEMM (unchanged from R5/R8 best) ----------------
// 128x128 tile, BK=64, 256 threads = 4 waves (2x2 of 64x64). 2 buffers x 32KB
// = 64KB LDS -> 2 blocks/CU co-resident. Grid 512 = exactly 2/CU. Counted
// vmcnt(8) keeps next tile's 8 gloads in flight across the barrier.
__global__ __launch_bounds__(256, 2) void mfma_gemm_bt4(
    const __bf16* __restrict__ A, const __bf16* __restrict__ B,
    float* __restrict__ C, int lda, int ldb, int ldc, int kiters) {
  __shared__ __align__(16) __bf16 lds[2 * 16384];  // 64 KB: [buf][A 8192 | B 8192]
  const int tid = threadIdx.x;
  const int wave = tid >> 6;
  const int lane = tid & 63;

  // XCD chunking: 512 wgs, 8 XCDs -> 64 consecutive ids per XCD, shaped 8Mx8N.
  const int wg = blockIdx.x + (blockIdx.y << 5);  // 32 M-tiles x 16 N-tiles
  const int xcd = wg & 7, loc = wg >> 3;          // loc 0..63
  const int tm = ((xcd & 3) * 8 + (loc >> 3)) * 128;
  const int tn = ((xcd >> 2) * 8 + (loc & 7)) * 128;

  const int srow = lane >> 3;                 // row within 8-row staging chunk
  const int skoff = ((lane & 7) ^ srow) * 8;  // XOR-swizzled k offset (elems)

  const int wr = wave >> 1, wc = wave & 1;    // 2x2 wave grid of 64x64 tiles
  const int rlo = lane & 7;
  const int rb3 = (lane >> 3) & 1;
  const int qb = lane >> 4;

  f32x4 acc[4][4] = {};

  // stage tile kt into buffer buf: 32 chunks ([8 rows][64 k] each), 8/wave
  auto stage = [&](int buf, int kt) {
    const int kc = kt * 64;
    __bf16* Ls = lds + buf * 16384;
#pragma unroll
    for (int r = 0; r < 4; ++r) {
      const int ch = wave + r * 4;  // A chunks 0..15 (rows tm..tm+127)
      ld_lds16(A + (size_t)(tm + ch * 8 + srow) * lda + kc + skoff, &Ls[ch * 512]);
    }
#pragma unroll
    for (int r = 0; r < 4; ++r) {
      const int ch = wave + r * 4;  // B chunks 0..15 (rows tn..tn+127)
      ld_lds16(B + (size_t)(tn + ch * 8 + srow) * ldb + kc + skoff,
               &Ls[8192 + ch * 512]);
    }
  };

  stage(0, 0);  // prologue: tile 0 in flight

  for (int kt = 0; kt < kiters; ++kt) {
    const int cb = kt & 1;
    if (kt + 1 < kiters) {
      stage(cb ^ 1, kt + 1);  // overwrites buffer read at kt-1 (barrier-safe)
      asm volatile("s_waitcnt vmcnt(8)" ::: "memory");  // tile kt landed
    } else {
      asm volatile("s_waitcnt vmcnt(0)" ::: "memory");
    }
    __builtin_amdgcn_s_barrier();

    const __bf16* As = lds + cb * 16384;
    const __bf16* Bs = As + 8192;
#pragma unroll
    for (int ks = 0; ks < 2; ++ks) {
      bf16x8 af[4], bfg[4];
      const int q8 = ((ks * 4 + qb) ^ rlo) * 8;
#pragma unroll
      for (int i = 0; i < 4; ++i) {
        const int rh = wr * 8 + i * 2 + rb3;
        af[i] = *(const bf16x8*)&As[rh * 512 + rlo * 64 + q8];
      }
#pragma unroll
      for (int j = 0; j < 4; ++j) {
        const int rh = wc * 8 + j * 2 + rb3;
        bfg[j] = *(const bf16x8*)&Bs[rh * 512 + rlo * 64 + q8];
      }
      __builtin_amdgcn_s_setprio(1);
#pragma unroll
      for (int i = 0; i < 4; ++i)
#pragma unroll
        for (int j = 0; j < 4; ++j)
          acc[i][j] =
              __builtin_amdgcn_mfma_f32_16x16x32_bf16(af[i], bfg[j], acc[i][j], 0, 0, 0);
      __builtin_amdgcn_s_setprio(0);
    }
    __builtin_amdgcn_s_barrier();  // all reads of buf cb done before next overwrite
  }

  // C/D layout: col = lane&15, row = (lane>>4)*4 + reg
  const int crow0 = tm + wr * 64 + (lane >> 4) * 4;
  const int ccol0 = tn + wc * 64 + (lane & 15);
#pragma unroll
  for (int i = 0; i < 4; ++i)
#pragma unroll
    for (int j = 0; j < 4; ++j)
#pragma unroll
      for (int rg = 0; rg < 4; ++rg)
        C[(size_t)(crow0 + i * 16 + rg) * ldc + ccol0 + j * 16] = acc[i][j][rg];
}

extern "C" void kernel_launch(void* const* d_in, const int* in_sizes, int n_in,
                              void* d_out, int out_size, void* d_ws, size_t ws_size,
                              hipStream_t stream) {
  const float* x = (const float*)d_in[0];       // [2,2048,2048] -> [4096,2048]
  const float* weight = (const float*)d_in[1];  // [2048,2048]
  const float* gate_w = (const float*)d_in[2];  // [8,2048]
  const float* A_w = (const float*)d_in[3];     // [8,16,2048] == [128,2048]
  const float* B_w = (const float*)d_in[4];     // [8,2048,16]
  float* out = (float*)d_out;                   // [4096,2048]

  char* ws = (char*)d_ws;
  __bf16* Abuf = (__bf16*)ws;                // [4096,2176] bf16 = 17,825,792 B
  __bf16* Bfull = (__bf16*)(ws + 17825792);  // [2048,2176] bf16 =  8,912,896 B
  __bf16* A2 = (__bf16*)(ws + 26738688);     // [128,2048]  bf16 =    524,288 B

  // 0. tiny: A_w -> A2 (breaks the cross-block race for the fused dispatch)
  a2_prep<<<128, 256, 0, stream>>>(A_w, A2);
  // 1. fused: router blocks (1/CU) + prep blocks co-resident in slot 2
  fused_pre<<<1312, 512, 0, stream>>>(x, gate_w, A2, weight, B_w, Abuf, Bfull);
  // 2. out = Abuf @ Bfull^T  (K=2176 fuses base + LoRA-up)
  mfma_gemm_bt4<<<dim3(32, 16), 256, 0, stream>>>(Abuf, Bfull, out, 2176, 2176,
                                                  2048, 34);
}